// Round 7
// baseline (2118.742 us; speedup 1.0000x reference)
//
#include <hip/hip_runtime.h>
#include <math.h>

#define BB 128
#define QQ 200
#define CC 92
#define CMPAD (QQ * QQ + 64) // pad so c3 = crow[192+t] stays in-bounds for t<64

// ---------------------------------------------------------------------------
__device__ __forceinline__ int rdlane_i(int x, int l) { return __builtin_amdgcn_readlane(x, l); }
__device__ __forceinline__ float rdlane_f(float x, int l) {
    return __uint_as_float((unsigned)__builtin_amdgcn_readlane((int)__float_as_uint(x), l));
}

// wave64 float min-reduce via DPP (row_shr 1/2/4/8, row_bcast 15/31), result
// broadcast from lane 63 as an SGPR. Float domain (v_min_f32): jnp.argmin
// compares floats, so equality-ballot against this min reproduces its
// semantics exactly (incl. -0==+0). No NaNs in this data.
__device__ __forceinline__ float wave_fmin_bcast(float x) {
    float y;
#define DPPSTEP(ctrl) \
    y = __uint_as_float((unsigned)__builtin_amdgcn_update_dpp( \
            (int)__float_as_uint(x), (int)__float_as_uint(x), ctrl, 0xf, 0xf, false)); \
    x = fminf(x, y);
    DPPSTEP(0x111) DPPSTEP(0x112) DPPSTEP(0x114) DPPSTEP(0x118)
    DPPSTEP(0x142) DPPSTEP(0x143)
#undef DPPSTEP
    return rdlane_f(x, 63);
}

// ---------------------------------------------------------------------------
// Fused kernel, R16 = R14 (256 threads, 4-wave prologue, R12 main loop) plus
// RUNNER-UP ROW SPECULATION in the main loop:
//   At iteration n, besides j1 = argmin(kv), compute j2 = argmin(kv with
//   column j1 masked to INF) during the ds_read shadow, and prefetch row
//   p[j2] into spec registers. At iteration n+1, minv' = minv - delta is
//   order-preserving, so if the newly scanned row does not produce the
//   winner, the winner is EXACTLY j2: if (j1' == j2) the row data is already
//   in registers and the ~120cyc LDS wait disappears from the carried chain.
//   On miss, the normal read is issued (before the spec read, so in-order DS
//   returns let the compiler wait with lgkmcnt(4)).
// Value-safety: spec changes only WHERE identical bits come from. p[j2] and
// u[p[j2]] are stable between spec-read and use (p changes only at augment;
// u[p[j]] updates only for used j, and j2 is unused). Trajectory
// bit-identical to the reference by construction.
// Lane t owns columns j = 1+t+64k (k=0..3; k=3 valid only for t<8).
// ---------------------------------------------------------------------------
__global__ __launch_bounds__(256) void hungarian_fused(const float* __restrict__ pc,
                                                       const float* __restrict__ pb,
                                                       const int*   __restrict__ tc,
                                                       const float* __restrict__ tb,
                                                       float* __restrict__ out) {
    const int b = blockIdx.x;
    const int tid = threadIdx.x;
    const int w = tid >> 6;         // wave id 0..3
    const int t = tid & 63;         // lane id

    __shared__ __align__(16) float cm[CMPAD];
    __shared__ float lse_s[QQ];

    const float INF = 1e9f;
    const int nval = (t < 8) ? 4 : 3;   // slot k valid iff t+64k < 200

    // ---- per-lane column constants (owned columns j = t+64k); same per wave
    int   cls[4];
    float tbx[4][4];
#pragma unroll
    for (int k = 0; k < 4; ++k) {
        if (k < nval) {
            int jj = t + 64 * k;
            cls[k] = tc[b * QQ + jj];
            const float4 v4 = *reinterpret_cast<const float4*>(tb + ((size_t)(b * QQ + jj)) * 4);
            tbx[k][0] = v4.x; tbx[k][1] = v4.y; tbx[k][2] = v4.z; tbx[k][3] = v4.w;
        } else {
            cls[k] = 0;
            tbx[k][0] = tbx[k][1] = tbx[k][2] = tbx[k][3] = 0.f;
        }
    }

    // ---- lse: one row per thread (200 <= 256), same op order as reference
    if (tid < QQ) {
        const float* row = pc + ((size_t)(b * QQ + tid)) * CC;
        float m = -INFINITY;
        for (int c = 0; c < CC; ++c) m = fmaxf(m, row[c]);
        float s = 0.f;
        for (int c = 0; c < CC; ++c) s += expf(row[c] - m);
        lse_s[tid] = m + logf(s);
    }
    __syncthreads();

    // ---- cost rows into cm: wave w fills rows i = w, w+4, ... (50 each);
    //      identical per-element fp expression/order as reference
    for (int i = w; i < QQ; i += 4) {
        const float4 pb4 = *reinterpret_cast<const float4*>(pb + ((size_t)(b * QQ + i)) * 4);
        const float pbb[4] = {pb4.x, pb4.y, pb4.z, pb4.w};
        const float lsei = lse_s[i];
        const float* pcrow = pc + ((size_t)(b * QQ + i)) * CC;
#pragma unroll
        for (int k = 0; k < 4; ++k) {
            if (k < nval) {
                float ce = lsei - pcrow[cls[k]];
                float sl1 = 0.f;
#pragma unroll
                for (int d = 0; d < 4; ++d) {
                    float df = pbb[d] - tbx[k][d];
                    float ad = fabsf(df);
                    sl1 += (ad < 1.f) ? 0.5f * df * df : (ad - 0.5f);
                }
                float mask = (cls[k] != 0) ? 1.f : 0.f;
                cm[i * QQ + t + 64 * k] = ce + sl1 * mask;
            }
        }
    }
    __syncthreads();

    // ---- waves 1-3 done (no barriers below, so early exit is legal)
    if (tid >= 64) return;

    // =======================================================================
    // Hungarian main loop — R12 machinery + runner-up speculation.
    // =======================================================================
    float v[4]     = {0.f, 0.f, 0.f, 0.f};
    int   pslot[4] = {0, 0, 0, 0};      // p for owned columns (0 = free)
    unsigned pp    = 0u;                // packed u8 shadow of pslot
    float uslot[4] = {0.f, 0.f, 0.f, 0.f};  // u of row matched to owned column
    float minv[4];
    int   waysl[4];
    int   usedm;
    float usent;

    for (int i = 1; i <= QQ; ++i) {
        minv[0] = minv[1] = minv[2] = minv[3] = INF;
        waysl[0] = waysl[1] = waysl[2] = waysl[3] = 0;
        usedm = 0;
        usent = 0.f;                    // u[i] == 0 at phase start
        int j0 = 0;
        float u0 = 0.f;                 // u[i0] for current iteration
        const float* crow = cm + (i - 1) * QQ;
        float c0 = crow[t];
        float c1 = crow[64 + t];
        float c2 = crow[128 + t];
        float c3 = crow[192 + t];       // pad keeps this in-bounds

        // spec state (reset per phase; first iteration is always a miss)
        int   j2p = 0;                  // predicted next column (0 = none)
        int   spi = 0;                  // p[j2p] captured at spec time
        float su0 = 0.f;                // u[p[j2p]] captured at spec time
        float s0 = 0.f, s1 = 0.f, s2 = 0.f, s3 = 0.f;  // spec row data

        for (;;) {
            // ---- mark j0 used (owner lane)
            if (j0 > 0) {
                int s = (j0 - 1) >> 6;
                if (((j0 - 1) & 63) == t) usedm |= 1 << s;
            }

            // ---- scan owned columns (gated on !used: way entries freeze)
            float kv0, kv1, kv2, kv3;
            {
                float cur;
                cur = c0 - u0 - v[0];
                if (!(usedm & 1) && cur < minv[0]) { minv[0] = cur; waysl[0] = j0; }
                kv0 = (usedm & 1) ? INF : minv[0];
                cur = c1 - u0 - v[1];
                if (!(usedm & 2) && cur < minv[1]) { minv[1] = cur; waysl[1] = j0; }
                kv1 = (usedm & 2) ? INF : minv[1];
                cur = c2 - u0 - v[2];
                if (!(usedm & 4) && cur < minv[2]) { minv[2] = cur; waysl[2] = j0; }
                kv2 = (usedm & 4) ? INF : minv[2];
                cur = c3 - u0 - v[3];
                if (!(usedm & 8) && t < 8 && cur < minv[3]) { minv[3] = cur; waysl[3] = j0; }
                kv3 = ((usedm & 8) || t >= 8) ? INF : minv[3];
            }

            float gmin = wave_fmin_bcast(fminf(fminf(kv0, kv1), fminf(kv2, kv3)));
            float delta = gmin;

            // ---- smallest j with kv==gmin: k-major, lowest lane
            unsigned long long m0 = __ballot(kv0 == gmin);
            unsigned long long m1 = __ballot(kv1 == gmin);
            unsigned long long m2 = __ballot(kv2 == gmin);
            unsigned long long m3 = __ballot(kv3 == gmin);
            int j1;
            if (m0)      j1 = 1   + (int)__builtin_ctzll(m0);
            else if (m1) j1 = 65  + (int)__builtin_ctzll(m1);
            else if (m2) j1 = 129 + (int)__builtin_ctzll(m2);
            else         j1 = 193 + (int)__builtin_ctzll(m3);

            int kk = (j1 - 1) >> 6, ln = (j1 - 1) & 63;

            // ---- row data for next iteration: spec hit or fresh read
            int pi;
            float n0, n1, n2, n3, u0n;
            bool hit = (j1 == j2p);     // wave-uniform
            if (hit) {
                pi = spi;               // p[j2p] captured earlier, stable
                n0 = s0; n1 = s1; n2 = s2; n3 = s3;
                u0n = su0;              // u[p[j2p]] stable (j2p was unused)
            } else {
                float us = (kk == 0) ? uslot[0] : (kk == 1) ? uslot[1]
                          : (kk == 2) ? uslot[2] : uslot[3];
                pi = (int)(((unsigned)rdlane_i((int)pp, ln) >> (kk * 8)) & 255u);
                int nr = (pi > 0 ? pi : 1) - 1;
                const float* nrow = cm + nr * QQ;
                n0 = nrow[t];
                n1 = nrow[64 + t];
                n2 = nrow[128 + t];
                n3 = nrow[192 + t];
                u0n = rdlane_f(us, ln);
            }

            // ---- updates (identical fp-op sequence to reference)
#pragma unroll
            for (int k = 0; k < 4; ++k) {
                if (usedm & (1 << k)) {
                    v[k] -= delta;
                    uslot[k] += delta;               // == u[p[j]] += delta
                } else if (k < nval) {
                    minv[k] -= delta;
                }
            }
            usent += delta;                          // == u[i] += delta (sentinel)

            // ---- speculate next winner: runner-up column j2 (issue its row
            //      read now; lands in the shadow). minv' = minv - delta is
            //      order-preserving, so if the next row doesn't win, the next
            //      j1 is exactly j2. All-INF/garbage cases just miss later.
            {
                float q0 = kv0, q1 = kv1, q2 = kv2, q3 = kv3;
                bool me = (t == ln);
                if (me & (kk == 0)) q0 = INF;
                if (me & (kk == 1)) q1 = INF;
                if (me & (kk == 2)) q2 = INF;
                if (me & (kk == 3)) q3 = INF;
                float g2 = wave_fmin_bcast(fminf(fminf(q0, q1), fminf(q2, q3)));
                unsigned long long b0 = __ballot(q0 == g2);
                unsigned long long b1 = __ballot(q1 == g2);
                unsigned long long b2 = __ballot(q2 == g2);
                unsigned long long b3 = __ballot(q3 == g2);
                int j2;
                if (b0)      j2 = 1   + (int)__builtin_ctzll(b0);
                else if (b1) j2 = 65  + (int)__builtin_ctzll(b1);
                else if (b2) j2 = 129 + (int)__builtin_ctzll(b2);
                else         j2 = 193 + (int)__builtin_ctzll(b3);
                int k2 = (j2 - 1) >> 6, l2 = (j2 - 1) & 63;
                spi = (int)(((unsigned)rdlane_i((int)pp, l2) >> (k2 * 8)) & 255u);
                int nr2 = (spi > 0 ? spi : 1) - 1;
                const float* srow = cm + nr2 * QQ;
                s0 = srow[t];
                s1 = srow[64 + t];
                s2 = srow[128 + t];
                s3 = srow[192 + t];
                float us2 = (k2 == 0) ? uslot[0] : (k2 == 1) ? uslot[1]
                           : (k2 == 2) ? uslot[2] : uslot[3];
                su0 = rdlane_f(us2, l2);
                j2p = j2;
            }

            if (pi == 0) { j0 = j1; break; }
            j0 = j1; u0 = u0n;
            c0 = n0; c1 = n1; c2 = n2; c3 = n3;
        }

        // ---- augment: flip matching along alternating path (uniform walk;
        //      way/p/u served from registers via readlane; entries frozen)
        {
            int jj = j0;
            while (jj != 0) {
                int jm = jj - 1, km = jm >> 6, lm = jm & 63;
                int ws = (km == 0) ? waysl[0] : (km == 1) ? waysl[1]
                        : (km == 2) ? waysl[2] : waysl[3];
                int jn = rdlane_i(ws, lm);
                int pnew; float unew;
                if (jn == 0) {
                    pnew = i;                        // p[0] = i (sentinel)
                    unew = usent;                    // u[i] accumulated this phase
                } else {
                    int jm2 = jn - 1, kn = jm2 >> 6, ln2 = jm2 & 63;
                    int   ps2 = (kn == 0) ? pslot[0] : (kn == 1) ? pslot[1]
                               : (kn == 2) ? pslot[2] : pslot[3];
                    float us2 = (kn == 0) ? uslot[0] : (kn == 1) ? uslot[1]
                               : (kn == 2) ? uslot[2] : uslot[3];
                    pnew = rdlane_i(ps2, ln2);
                    unew = rdlane_f(us2, ln2);
                }
                if (lm == t) {
                    pslot[km] = pnew;
                    uslot[km] = unew;
                    int sh = km * 8;
                    pp = (pp & ~(255u << sh)) | ((unsigned)pnew << sh);
                }
                jj = jn;
            }
        }
    }

    // pslot[k] = row matched to owned column jc; emit per-row matched cost
#pragma unroll
    for (int k = 0; k < 4; ++k) {
        if (k < nval) {
            int jc = 1 + t + 64 * k;
            int row = pslot[k] - 1;
            out[b * QQ + row] = cm[row * QQ + (jc - 1)];
        }
    }
}

// ---------------------------------------------------------------------------
extern "C" void kernel_launch(void* const* d_in, const int* in_sizes, int n_in,
                              void* d_out, int out_size, void* d_ws, size_t ws_size,
                              hipStream_t stream) {
    const float* pred_cat  = (const float*)d_in[0];
    const float* pred_bbox = (const float*)d_in[1];
    const int*   tar_cat   = (const int*)d_in[2];
    const float* tar_bbox  = (const float*)d_in[3];
    float* out = (float*)d_out;
    (void)d_ws; (void)ws_size;

    hungarian_fused<<<BB, 256, 0, stream>>>(pred_cat, pred_bbox, tar_cat, tar_bbox, out);
}

// Round 8
// 1429.056 us; speedup vs baseline: 1.4826x; 1.4826x over previous
//
#include <hip/hip_runtime.h>
#include <math.h>

#define BB 128
#define QQ 200
#define CC 92
#define CMPAD (QQ * QQ + 64) // pad so c3 = crow[192+t] stays in-bounds for t<64

// ---------------------------------------------------------------------------
__device__ __forceinline__ int rdlane_i(int x, int l) { return __builtin_amdgcn_readlane(x, l); }
__device__ __forceinline__ float rdlane_f(float x, int l) {
    return __uint_as_float((unsigned)__builtin_amdgcn_readlane((int)__float_as_uint(x), l));
}

// wave64 float min-reduce via DPP (row_shr 1/2/4/8, row_bcast 15/31), result
// broadcast from lane 63 as an SGPR. Float domain (v_min_f32): jnp.argmin
// compares floats, so equality-ballot against this min reproduces its
// semantics exactly (incl. -0==+0). No NaNs in this data.
__device__ __forceinline__ float wave_fmin_bcast(float x) {
    float y;
#define DPPSTEP(ctrl) \
    y = __uint_as_float((unsigned)__builtin_amdgcn_update_dpp( \
            (int)__float_as_uint(x), (int)__float_as_uint(x), ctrl, 0xf, 0xf, false)); \
    x = fminf(x, y);
    DPPSTEP(0x111) DPPSTEP(0x112) DPPSTEP(0x114) DPPSTEP(0x118)
    DPPSTEP(0x142) DPPSTEP(0x143)
#undef DPPSTEP
    return rdlane_f(x, 63);
}

// ---------------------------------------------------------------------------
// Fused kernel, R17 = R14 (256 threads, 4-wave prologue, R12 main loop;
// measured 1331us dispatch) + phase-boundary row prefetch as the single
// isolated change. R11's correctness failure is root-caused to ungated-scan
// + uninitialized LDS pad (R11 dropped R10's pad-fill), NOT this prefetch:
// here the scan keeps R12's t<8 gating so pad values never reach minv, and
// all pad reads are in-bounds (max idx 199*200+192+63 = 40055 < 40064).
//   - c0..c3 hoisted out of the phase loop; row 0 prefetched before phase 1
//   - phase i+1's row loaded BEFORE the augment walk, so its ~120cyc LDS
//     latency hides under the register-only augment pointer chase
// Everything else is byte-for-byte R14. Trajectory bit-identical.
// Lane t owns columns j = 1+t+64k (k=0..3; k=3 valid only for t<8).
// ---------------------------------------------------------------------------
__global__ __launch_bounds__(256) void hungarian_fused(const float* __restrict__ pc,
                                                       const float* __restrict__ pb,
                                                       const int*   __restrict__ tc,
                                                       const float* __restrict__ tb,
                                                       float* __restrict__ out) {
    const int b = blockIdx.x;
    const int tid = threadIdx.x;
    const int w = tid >> 6;         // wave id 0..3
    const int t = tid & 63;         // lane id

    __shared__ __align__(16) float cm[CMPAD];
    __shared__ float lse_s[QQ];

    const float INF = 1e9f;
    const int nval = (t < 8) ? 4 : 3;   // slot k valid iff t+64k < 200

    // ---- per-lane column constants (owned columns j = t+64k); same per wave
    int   cls[4];
    float tbx[4][4];
#pragma unroll
    for (int k = 0; k < 4; ++k) {
        if (k < nval) {
            int jj = t + 64 * k;
            cls[k] = tc[b * QQ + jj];
            const float4 v4 = *reinterpret_cast<const float4*>(tb + ((size_t)(b * QQ + jj)) * 4);
            tbx[k][0] = v4.x; tbx[k][1] = v4.y; tbx[k][2] = v4.z; tbx[k][3] = v4.w;
        } else {
            cls[k] = 0;
            tbx[k][0] = tbx[k][1] = tbx[k][2] = tbx[k][3] = 0.f;
        }
    }

    // ---- lse: one row per thread (200 <= 256), same op order as reference
    if (tid < QQ) {
        const float* row = pc + ((size_t)(b * QQ + tid)) * CC;
        float m = -INFINITY;
        for (int c = 0; c < CC; ++c) m = fmaxf(m, row[c]);
        float s = 0.f;
        for (int c = 0; c < CC; ++c) s += expf(row[c] - m);
        lse_s[tid] = m + logf(s);
    }
    __syncthreads();

    // ---- cost rows into cm: wave w fills rows i = w, w+4, ... (50 each);
    //      identical per-element fp expression/order as reference
    for (int i = w; i < QQ; i += 4) {
        const float4 pb4 = *reinterpret_cast<const float4*>(pb + ((size_t)(b * QQ + i)) * 4);
        const float pbb[4] = {pb4.x, pb4.y, pb4.z, pb4.w};
        const float lsei = lse_s[i];
        const float* pcrow = pc + ((size_t)(b * QQ + i)) * CC;
#pragma unroll
        for (int k = 0; k < 4; ++k) {
            if (k < nval) {
                float ce = lsei - pcrow[cls[k]];
                float sl1 = 0.f;
#pragma unroll
                for (int d = 0; d < 4; ++d) {
                    float df = pbb[d] - tbx[k][d];
                    float ad = fabsf(df);
                    sl1 += (ad < 1.f) ? 0.5f * df * df : (ad - 0.5f);
                }
                float mask = (cls[k] != 0) ? 1.f : 0.f;
                cm[i * QQ + t + 64 * k] = ce + sl1 * mask;
            }
        }
    }
    __syncthreads();

    // ---- waves 1-3 done (no barriers below, so early exit is legal)
    if (tid >= 64) return;

    // =======================================================================
    // Hungarian main loop — R12 machinery (trajectory bit-for-bit vs
    // reference) with c0..c3 carried across phases (prefetch under augment).
    // =======================================================================
    float v[4]     = {0.f, 0.f, 0.f, 0.f};
    int   pslot[4] = {0, 0, 0, 0};      // p for owned columns (0 = free)
    unsigned pp    = 0u;                // packed u8 shadow of pslot
    float uslot[4] = {0.f, 0.f, 0.f, 0.f};  // u of row matched to owned column
    float minv[4];
    int   waysl[4];
    int   usedm;
    float usent;

    // prefetch phase-1 row (row 0)
    float c0 = cm[t];
    float c1 = cm[64 + t];
    float c2 = cm[128 + t];
    float c3 = cm[192 + t];             // pad keeps this in-bounds

    for (int i = 1; i <= QQ; ++i) {
        minv[0] = minv[1] = minv[2] = minv[3] = INF;
        waysl[0] = waysl[1] = waysl[2] = waysl[3] = 0;
        usedm = 0;
        usent = 0.f;                    // u[i] == 0 at phase start
        int j0 = 0;
        float u0 = 0.f;                 // u[i0] for current iteration

        for (;;) {
            // ---- mark j0 used (owner lane)
            if (j0 > 0) {
                int s = (j0 - 1) >> 6;
                if (((j0 - 1) & 63) == t) usedm |= 1 << s;
            }

            // ---- scan owned columns (gated on !used: way entries freeze)
            float kv0, kv1, kv2, kv3;
            {
                float cur;
                cur = c0 - u0 - v[0];
                if (!(usedm & 1) && cur < minv[0]) { minv[0] = cur; waysl[0] = j0; }
                kv0 = (usedm & 1) ? INF : minv[0];
                cur = c1 - u0 - v[1];
                if (!(usedm & 2) && cur < minv[1]) { minv[1] = cur; waysl[1] = j0; }
                kv1 = (usedm & 2) ? INF : minv[1];
                cur = c2 - u0 - v[2];
                if (!(usedm & 4) && cur < minv[2]) { minv[2] = cur; waysl[2] = j0; }
                kv2 = (usedm & 4) ? INF : minv[2];
                cur = c3 - u0 - v[3];
                if (!(usedm & 8) && t < 8 && cur < minv[3]) { minv[3] = cur; waysl[3] = j0; }
                kv3 = ((usedm & 8) || t >= 8) ? INF : minv[3];
            }

            float gmin = wave_fmin_bcast(fminf(fminf(kv0, kv1), fminf(kv2, kv3)));
            float delta = gmin;

            // ---- smallest j with kv==gmin: k-major, lowest lane
            unsigned long long m0 = __ballot(kv0 == gmin);
            unsigned long long m1 = __ballot(kv1 == gmin);
            unsigned long long m2 = __ballot(kv2 == gmin);
            unsigned long long m3 = __ballot(kv3 == gmin);
            int j1;
            if (m0)      j1 = 1   + (int)__builtin_ctzll(m0);
            else if (m1) j1 = 65  + (int)__builtin_ctzll(m1);
            else if (m2) j1 = 129 + (int)__builtin_ctzll(m2);
            else         j1 = 193 + (int)__builtin_ctzll(m3);

            // ---- matched row + its dual from j1's owner lane (j1 uniform)
            int kk = (j1 - 1) >> 6, ln = (j1 - 1) & 63;
            float us = (kk == 0) ? uslot[0] : (kk == 1) ? uslot[1]
                      : (kk == 2) ? uslot[2] : uslot[3];
            // fast path: packed shadow, no select chain ahead of the readlane
            int pi = (int)(((unsigned)rdlane_i((int)pp, ln) >> (kk * 8)) & 255u);

            // ---- issue next row's reads NOW (cm immutable: no hazard);
            //      ~120cyc latency overlaps updates + u0n readlane below
            int nr = (pi > 0 ? pi : 1) - 1;
            const float* nrow = cm + nr * QQ;
            float n0 = nrow[t];
            float n1 = nrow[64 + t];
            float n2 = nrow[128 + t];
            float n3 = nrow[192 + t];

            float u0n = rdlane_f(us, ln);

            // ---- updates (identical fp-op sequence to reference)
#pragma unroll
            for (int k = 0; k < 4; ++k) {
                if (usedm & (1 << k)) {
                    v[k] -= delta;
                    uslot[k] += delta;               // == u[p[j]] += delta
                } else if (k < nval) {
                    minv[k] -= delta;
                }
            }
            usent += delta;                          // == u[i] += delta (sentinel)

            if (pi == 0) { j0 = j1; break; }
            j0 = j1; u0 = u0n;
            c0 = n0; c1 = n1; c2 = n2; c3 = n3;
        }

        // ---- prefetch next phase's row; LDS latency hides under the augment
        if (i < QQ) {
            const float* prow = cm + i * QQ;       // row (i+1)-1, 0-based
            c0 = prow[t];
            c1 = prow[64 + t];
            c2 = prow[128 + t];
            c3 = prow[192 + t];
        }

        // ---- augment: flip matching along alternating path (uniform walk;
        //      way/p/u served from registers via readlane; entries frozen)
        {
            int jj = j0;
            while (jj != 0) {
                int jm = jj - 1, km = jm >> 6, lm = jm & 63;
                int ws = (km == 0) ? waysl[0] : (km == 1) ? waysl[1]
                        : (km == 2) ? waysl[2] : waysl[3];
                int jn = rdlane_i(ws, lm);
                int pnew; float unew;
                if (jn == 0) {
                    pnew = i;                        // p[0] = i (sentinel)
                    unew = usent;                    // u[i] accumulated this phase
                } else {
                    int jm2 = jn - 1, kn = jm2 >> 6, ln2 = jm2 & 63;
                    int   ps2 = (kn == 0) ? pslot[0] : (kn == 1) ? pslot[1]
                               : (kn == 2) ? pslot[2] : pslot[3];
                    float us2 = (kn == 0) ? uslot[0] : (kn == 1) ? uslot[1]
                               : (kn == 2) ? uslot[2] : uslot[3];
                    pnew = rdlane_i(ps2, ln2);
                    unew = rdlane_f(us2, ln2);
                }
                if (lm == t) {
                    pslot[km] = pnew;
                    uslot[km] = unew;
                    int sh = km * 8;
                    pp = (pp & ~(255u << sh)) | ((unsigned)pnew << sh);
                }
                jj = jn;
            }
        }
    }

    // pslot[k] = row matched to owned column jc; emit per-row matched cost
#pragma unroll
    for (int k = 0; k < 4; ++k) {
        if (k < nval) {
            int jc = 1 + t + 64 * k;
            int row = pslot[k] - 1;
            out[b * QQ + row] = cm[row * QQ + (jc - 1)];
        }
    }
}

// ---------------------------------------------------------------------------
extern "C" void kernel_launch(void* const* d_in, const int* in_sizes, int n_in,
                              void* d_out, int out_size, void* d_ws, size_t ws_size,
                              hipStream_t stream) {
    const float* pred_cat  = (const float*)d_in[0];
    const float* pred_bbox = (const float*)d_in[1];
    const int*   tar_cat   = (const int*)d_in[2];
    const float* tar_bbox  = (const float*)d_in[3];
    float* out = (float*)d_out;
    (void)d_ws; (void)ws_size;

    hungarian_fused<<<BB, 256, 0, stream>>>(pred_cat, pred_bbox, tar_cat, tar_bbox, out);
}

// Round 9
// 1409.950 us; speedup vs baseline: 1.5027x; 1.0136x over previous
//
#include <hip/hip_runtime.h>
#include <math.h>

#define BB 128
#define QQ 200
#define CC 92
#define CMPAD (QQ * QQ + 64) // pad so c3 = crow[192+t] stays in-bounds for t<64

// ---------------------------------------------------------------------------
__device__ __forceinline__ int rdlane_i(int x, int l) { return __builtin_amdgcn_readlane(x, l); }
__device__ __forceinline__ float rdlane_f(float x, int l) {
    return __uint_as_float((unsigned)__builtin_amdgcn_readlane((int)__float_as_uint(x), l));
}

// wave64 float min-reduce via DPP (row_shr 1/2/4/8, row_bcast 15/31), result
// broadcast from lane 63 as an SGPR. Float domain (v_min_f32): jnp.argmin
// compares floats, so equality-ballot against this min reproduces its
// semantics exactly (incl. -0==+0). No NaNs in this data.
__device__ __forceinline__ float wave_fmin_bcast(float x) {
    float y;
#define DPPSTEP(ctrl) \
    y = __uint_as_float((unsigned)__builtin_amdgcn_update_dpp( \
            (int)__float_as_uint(x), (int)__float_as_uint(x), ctrl, 0xf, 0xf, false)); \
    x = fminf(x, y);
    DPPSTEP(0x111) DPPSTEP(0x112) DPPSTEP(0x114) DPPSTEP(0x118)
    DPPSTEP(0x142) DPPSTEP(0x143)
#undef DPPSTEP
    return rdlane_f(x, 63);
}

// ---------------------------------------------------------------------------
// Fused kernel, R18 = R14's main loop (byte-for-byte; phase-local crow loads
// are load-bearing -- carrying c0..c3 across phases regressed twice, R10/R17)
// + PRODUCER/CONSUMER OVERLAP of the cost fill:
//   Phase i of the JV loop only reads rows 0..i-1 (p[j] = rows matched in
//   earlier phases). Consumption ~6.4us/phase; fill ~1us/row. So waves 1-3
//   stream rows 0..199 in ascending order (blocks 67/67/66) WHILE wave 0
//   solves; after ~2 phases the fill is fully hidden.
//   - producers: lane-per-row lse (same sequential op order => bit-identical),
//     lse broadcast via readlane (no lse_s array); fill rows ascending with
//     R14's exact per-element expression; then s_waitcnt lgkmcnt(0) (LDS-only
//     drain; NOT threadfence_block which also drains vmcnt) + rdy[i]=1.
//   - consumer: before phase i, vectorized poll: lane t reads rdy[wm+t],
//     ballot, advance wm by leading-ready count (64 rows per ds_read; ~4
//     rounds total). Compiler barrier keeps crow reads below the poll.
//   One __syncthreads (after rdy zeroing) before divergence; none after.
// Values and trajectory bit-identical to R14/reference: identical fp
// expressions, only the STAGING TIME changes, and rdy proves write<read.
// Lane t owns columns j = 1+t+64k (k=0..3; k=3 valid only for t<8).
// ---------------------------------------------------------------------------
__global__ __launch_bounds__(256) void hungarian_fused(const float* __restrict__ pc,
                                                       const float* __restrict__ pb,
                                                       const int*   __restrict__ tc,
                                                       const float* __restrict__ tb,
                                                       float* __restrict__ out) {
    const int b = blockIdx.x;
    const int tid = threadIdx.x;
    const int w = tid >> 6;         // wave id 0..3
    const int t = tid & 63;         // lane id

    __shared__ __align__(16) float cm[CMPAD];
    __shared__ int rdy[QQ];

    const float INF = 1e9f;
    const int nval = (t < 8) ? 4 : 3;   // slot k valid iff t+64k < 200

    if (tid < QQ) rdy[tid] = 0;
    __syncthreads();                    // only barrier; all threads reach it

    if (w > 0) {
        // ================= producers: waves 1..3 =================
        const int base  = (w - 1) * 67;           // 0, 67, 134
        const int count = (w == 3) ? 66 : 67;

        // per-lane column constants (owned columns j = t+64k)
        int   cls[4];
        float tbx[4][4];
#pragma unroll
        for (int k = 0; k < 4; ++k) {
            if (k < nval) {
                int jj = t + 64 * k;
                cls[k] = tc[b * QQ + jj];
                const float4 v4 = *reinterpret_cast<const float4*>(tb + ((size_t)(b * QQ + jj)) * 4);
                tbx[k][0] = v4.x; tbx[k][1] = v4.y; tbx[k][2] = v4.z; tbx[k][3] = v4.w;
            } else {
                cls[k] = 0;
                tbx[k][0] = tbx[k][1] = tbx[k][2] = tbx[k][3] = 0.f;
            }
        }

        // same sequential per-row op order as reference => bit-identical
        auto lse_row = [&](int r) -> float {
            const float* row = pc + ((size_t)(b * QQ + r)) * CC;
            float m = -INFINITY;
            for (int c = 0; c < CC; ++c) m = fmaxf(m, row[c]);
            float s = 0.f;
            for (int c = 0; c < CC; ++c) s += expf(row[c] - m);
            return m + logf(s);
        };

        // identical per-element fp expression/order as R14
        auto fill_row = [&](int i, float lsei) {
            const float4 pb4 = *reinterpret_cast<const float4*>(pb + ((size_t)(b * QQ + i)) * 4);
            const float pbb[4] = {pb4.x, pb4.y, pb4.z, pb4.w};
            const float* pcrow = pc + ((size_t)(b * QQ + i)) * CC;
#pragma unroll
            for (int k = 0; k < 4; ++k) {
                if (k < nval) {
                    float ce = lsei - pcrow[cls[k]];
                    float sl1 = 0.f;
#pragma unroll
                    for (int d = 0; d < 4; ++d) {
                        float df = pbb[d] - tbx[k][d];
                        float ad = fabsf(df);
                        sl1 += (ad < 1.f) ? 0.5f * df * df : (ad - 0.5f);
                    }
                    float mask = (cls[k] != 0) ? 1.f : 0.f;
                    cm[i * QQ + t + 64 * k] = ce + sl1 * mask;
                }
            }
            // drain this wave's LDS writes (lgkm only: keep global loads in
            // flight), then publish. "memory" clobber stops compiler motion.
            asm volatile("s_waitcnt lgkmcnt(0)" ::: "memory");
            if (t == 0) ((volatile int*)rdy)[i] = 1;
        };

        // pass 1: lse for rows base+t, then fill those rows ascending
        float lse_a = 0.f;
        if (t < count) lse_a = lse_row(base + t);
        const int n1 = (count < 64) ? count : 64;
        for (int r = 0; r < n1; ++r) fill_row(base + r, rdlane_f(lse_a, r));

        // pass 2: remaining rows (<=3)
        if (count > 64) {
            float lse_b = 0.f;
            if (64 + t < count) lse_b = lse_row(base + 64 + t);
            for (int r = 64; r < count; ++r) fill_row(base + r, rdlane_f(lse_b, r - 64));
        }
        return;
    }

    // ================= consumer: wave 0 — R14 main loop + poll =============
    float v[4]     = {0.f, 0.f, 0.f, 0.f};
    int   pslot[4] = {0, 0, 0, 0};      // p for owned columns (0 = free)
    unsigned pp    = 0u;                // packed u8 shadow of pslot
    float uslot[4] = {0.f, 0.f, 0.f, 0.f};  // u of row matched to owned column
    float minv[4];
    int   waysl[4];
    int   usedm;
    float usent;
    int   watermark = 0;                // rows 0..watermark-1 known staged

    for (int i = 1; i <= QQ; ++i) {
        // ---- wait until rows 0..i-1 staged (vector poll: 64 flags/ds_read)
        while (watermark < i) {
            int idx = watermark + t;
            int f = (idx < QQ) ? ((volatile int*)rdy)[idx] : 1;
            unsigned long long rm = __ballot(f != 0);
            unsigned long long nrm = ~rm;       // bit j set => lane j not ready
            int adv = nrm ? (int)__builtin_ctzll(nrm) : 64;
            if (adv == 0) __builtin_amdgcn_s_sleep(8);
            watermark += adv;
        }
        asm volatile("" ::: "memory");  // keep crow reads below the poll

        minv[0] = minv[1] = minv[2] = minv[3] = INF;
        waysl[0] = waysl[1] = waysl[2] = waysl[3] = 0;
        usedm = 0;
        usent = 0.f;                    // u[i] == 0 at phase start
        int j0 = 0;
        float u0 = 0.f;                 // u[i0] for current iteration
        const float* crow = cm + (i - 1) * QQ;
        float c0 = crow[t];
        float c1 = crow[64 + t];
        float c2 = crow[128 + t];
        float c3 = crow[192 + t];       // pad keeps this in-bounds

        for (;;) {
            // ---- mark j0 used (owner lane)
            if (j0 > 0) {
                int s = (j0 - 1) >> 6;
                if (((j0 - 1) & 63) == t) usedm |= 1 << s;
            }

            // ---- scan owned columns (gated on !used: way entries freeze)
            float kv0, kv1, kv2, kv3;
            {
                float cur;
                cur = c0 - u0 - v[0];
                if (!(usedm & 1) && cur < minv[0]) { minv[0] = cur; waysl[0] = j0; }
                kv0 = (usedm & 1) ? INF : minv[0];
                cur = c1 - u0 - v[1];
                if (!(usedm & 2) && cur < minv[1]) { minv[1] = cur; waysl[1] = j0; }
                kv1 = (usedm & 2) ? INF : minv[1];
                cur = c2 - u0 - v[2];
                if (!(usedm & 4) && cur < minv[2]) { minv[2] = cur; waysl[2] = j0; }
                kv2 = (usedm & 4) ? INF : minv[2];
                cur = c3 - u0 - v[3];
                if (!(usedm & 8) && t < 8 && cur < minv[3]) { minv[3] = cur; waysl[3] = j0; }
                kv3 = ((usedm & 8) || t >= 8) ? INF : minv[3];
            }

            float gmin = wave_fmin_bcast(fminf(fminf(kv0, kv1), fminf(kv2, kv3)));
            float delta = gmin;

            // ---- smallest j with kv==gmin: k-major, lowest lane
            unsigned long long m0 = __ballot(kv0 == gmin);
            unsigned long long m1 = __ballot(kv1 == gmin);
            unsigned long long m2 = __ballot(kv2 == gmin);
            unsigned long long m3 = __ballot(kv3 == gmin);
            int j1;
            if (m0)      j1 = 1   + (int)__builtin_ctzll(m0);
            else if (m1) j1 = 65  + (int)__builtin_ctzll(m1);
            else if (m2) j1 = 129 + (int)__builtin_ctzll(m2);
            else         j1 = 193 + (int)__builtin_ctzll(m3);

            // ---- matched row + its dual from j1's owner lane (j1 uniform)
            int kk = (j1 - 1) >> 6, ln = (j1 - 1) & 63;
            float us = (kk == 0) ? uslot[0] : (kk == 1) ? uslot[1]
                      : (kk == 2) ? uslot[2] : uslot[3];
            // fast path: packed shadow, no select chain ahead of the readlane
            int pi = (int)(((unsigned)rdlane_i((int)pp, ln) >> (kk * 8)) & 255u);

            // ---- issue next row's reads NOW (cm immutable: no hazard);
            //      ~120cyc latency overlaps updates + u0n readlane below
            int nr = (pi > 0 ? pi : 1) - 1;
            const float* nrow = cm + nr * QQ;
            float n0 = nrow[t];
            float n1 = nrow[64 + t];
            float n2 = nrow[128 + t];
            float n3 = nrow[192 + t];

            float u0n = rdlane_f(us, ln);

            // ---- updates (identical fp-op sequence to reference)
#pragma unroll
            for (int k = 0; k < 4; ++k) {
                if (usedm & (1 << k)) {
                    v[k] -= delta;
                    uslot[k] += delta;               // == u[p[j]] += delta
                } else if (k < nval) {
                    minv[k] -= delta;
                }
            }
            usent += delta;                          // == u[i] += delta (sentinel)

            if (pi == 0) { j0 = j1; break; }
            j0 = j1; u0 = u0n;
            c0 = n0; c1 = n1; c2 = n2; c3 = n3;
        }

        // ---- augment: flip matching along alternating path (uniform walk;
        //      way/p/u served from registers via readlane; entries frozen)
        {
            int jj = j0;
            while (jj != 0) {
                int jm = jj - 1, km = jm >> 6, lm = jm & 63;
                int ws = (km == 0) ? waysl[0] : (km == 1) ? waysl[1]
                        : (km == 2) ? waysl[2] : waysl[3];
                int jn = rdlane_i(ws, lm);
                int pnew; float unew;
                if (jn == 0) {
                    pnew = i;                        // p[0] = i (sentinel)
                    unew = usent;                    // u[i] accumulated this phase
                } else {
                    int jm2 = jn - 1, kn = jm2 >> 6, ln2 = jm2 & 63;
                    int   ps2 = (kn == 0) ? pslot[0] : (kn == 1) ? pslot[1]
                               : (kn == 2) ? pslot[2] : pslot[3];
                    float us2 = (kn == 0) ? uslot[0] : (kn == 1) ? uslot[1]
                               : (kn == 2) ? uslot[2] : uslot[3];
                    pnew = rdlane_i(ps2, ln2);
                    unew = rdlane_f(us2, ln2);
                }
                if (lm == t) {
                    pslot[km] = pnew;
                    uslot[km] = unew;
                    int sh = km * 8;
                    pp = (pp & ~(255u << sh)) | ((unsigned)pnew << sh);
                }
                jj = jn;
            }
        }
    }

    // pslot[k] = row matched to owned column jc; emit per-row matched cost
#pragma unroll
    for (int k = 0; k < 4; ++k) {
        if (k < nval) {
            int jc = 1 + t + 64 * k;
            int row = pslot[k] - 1;
            out[b * QQ + row] = cm[row * QQ + (jc - 1)];
        }
    }
}

// ---------------------------------------------------------------------------
extern "C" void kernel_launch(void* const* d_in, const int* in_sizes, int n_in,
                              void* d_out, int out_size, void* d_ws, size_t ws_size,
                              hipStream_t stream) {
    const float* pred_cat  = (const float*)d_in[0];
    const float* pred_bbox = (const float*)d_in[1];
    const int*   tar_cat   = (const int*)d_in[2];
    const float* tar_bbox  = (const float*)d_in[3];
    float* out = (float*)d_out;
    (void)d_ws; (void)ws_size;

    hungarian_fused<<<BB, 256, 0, stream>>>(pred_cat, pred_bbox, tar_cat, tar_bbox, out);
}

// Round 10
// 1393.832 us; speedup vs baseline: 1.5201x; 1.0116x over previous
//
#include <hip/hip_runtime.h>
#include <math.h>

#define BB 128
#define QQ 200
#define CC 92
#define CMPAD (QQ * QQ + 64) // pad so c3 = crow[192+t] stays in-bounds for t<64

// ---------------------------------------------------------------------------
__device__ __forceinline__ int rdlane_i(int x, int l) { return __builtin_amdgcn_readlane(x, l); }
__device__ __forceinline__ float rdlane_f(float x, int l) {
    return __uint_as_float((unsigned)__builtin_amdgcn_readlane((int)__float_as_uint(x), l));
}

// wave64 float min-reduce via DPP (row_shr 1/2/4/8, row_bcast 15/31), result
// broadcast from lane 63 as an SGPR. Float domain (v_min_f32): jnp.argmin
// compares floats, so equality-ballot against this min reproduces its
// semantics exactly (incl. -0==+0). No NaNs in this data.
__device__ __forceinline__ float wave_fmin_bcast(float x) {
    float y;
#define DPPSTEP(ctrl) \
    y = __uint_as_float((unsigned)__builtin_amdgcn_update_dpp( \
            (int)__float_as_uint(x), (int)__float_as_uint(x), ctrl, 0xf, 0xf, false)); \
    x = fminf(x, y);
    DPPSTEP(0x111) DPPSTEP(0x112) DPPSTEP(0x114) DPPSTEP(0x118)
    DPPSTEP(0x142) DPPSTEP(0x143)
#undef DPPSTEP
    return rdlane_f(x, 63);
}

// ---------------------------------------------------------------------------
// Fused kernel, R19 = R18 (producer/consumer overlap of the cost fill) with
// the two measured costs of R18 removed:
//   1. STRIDE-3 row interleave: wave w produces rows (w-1)+3m, so early rows
//      come from 3 waves in parallel (R18's contiguous blocks serialized
//      rows 0..66 behind wave 1 => ~30us watermark stall in early phases).
//   2. SCOPED clobber: the poll + asm memory barrier execute ONLY while
//      watermark < i. Once all 200 rows are staged (~phase 30), later phases
//      run R14's exact codegen (crow prefetch hoisting restored) -- R18's
//      unconditional clobber blocked it every phase.
// Row->wave assignment is value-irrelevant (same fp expressions => same
// bits); watermark advances only over the contiguous ready prefix, so
// write-before-read is proven. Main loop: byte-for-byte R14 (measured
// 1281us solve; trajectory bit-for-bit vs reference).
// Lane t owns columns j = 1+t+64k (k=0..3; k=3 valid only for t<8).
// ---------------------------------------------------------------------------
__global__ __launch_bounds__(256) void hungarian_fused(const float* __restrict__ pc,
                                                       const float* __restrict__ pb,
                                                       const int*   __restrict__ tc,
                                                       const float* __restrict__ tb,
                                                       float* __restrict__ out) {
    const int b = blockIdx.x;
    const int tid = threadIdx.x;
    const int w = tid >> 6;         // wave id 0..3
    const int t = tid & 63;         // lane id

    __shared__ __align__(16) float cm[CMPAD];
    __shared__ int rdy[QQ];

    const float INF = 1e9f;
    const int nval = (t < 8) ? 4 : 3;   // slot k valid iff t+64k < 200

    if (tid < QQ) rdy[tid] = 0;
    __syncthreads();                    // only barrier; all threads reach it

    if (w > 0) {
        // ================= producers: waves 1..3, rows (w-1)+3m ============
        const int start = w - 1;                    // 0,1,2
        const int count = (QQ - start + 2) / 3;     // 67,67,66

        // per-lane column constants (owned columns j = t+64k)
        int   cls[4];
        float tbx[4][4];
#pragma unroll
        for (int k = 0; k < 4; ++k) {
            if (k < nval) {
                int jj = t + 64 * k;
                cls[k] = tc[b * QQ + jj];
                const float4 v4 = *reinterpret_cast<const float4*>(tb + ((size_t)(b * QQ + jj)) * 4);
                tbx[k][0] = v4.x; tbx[k][1] = v4.y; tbx[k][2] = v4.z; tbx[k][3] = v4.w;
            } else {
                cls[k] = 0;
                tbx[k][0] = tbx[k][1] = tbx[k][2] = tbx[k][3] = 0.f;
            }
        }

        // same sequential per-row op order as reference => bit-identical
        auto lse_row = [&](int r) -> float {
            const float* row = pc + ((size_t)(b * QQ + r)) * CC;
            float m = -INFINITY;
            for (int c = 0; c < CC; ++c) m = fmaxf(m, row[c]);
            float s = 0.f;
            for (int c = 0; c < CC; ++c) s += expf(row[c] - m);
            return m + logf(s);
        };

        // identical per-element fp expression/order as R14
        auto fill_row = [&](int i, float lsei) {
            const float4 pb4 = *reinterpret_cast<const float4*>(pb + ((size_t)(b * QQ + i)) * 4);
            const float pbb[4] = {pb4.x, pb4.y, pb4.z, pb4.w};
            const float* pcrow = pc + ((size_t)(b * QQ + i)) * CC;
#pragma unroll
            for (int k = 0; k < 4; ++k) {
                if (k < nval) {
                    float ce = lsei - pcrow[cls[k]];
                    float sl1 = 0.f;
#pragma unroll
                    for (int d = 0; d < 4; ++d) {
                        float df = pbb[d] - tbx[k][d];
                        float ad = fabsf(df);
                        sl1 += (ad < 1.f) ? 0.5f * df * df : (ad - 0.5f);
                    }
                    float mask = (cls[k] != 0) ? 1.f : 0.f;
                    cm[i * QQ + t + 64 * k] = ce + sl1 * mask;
                }
            }
            // drain this wave's LDS writes (lgkm only: keep global loads in
            // flight), then publish. "memory" clobber stops compiler motion.
            asm volatile("s_waitcnt lgkmcnt(0)" ::: "memory");
            if (t == 0) ((volatile int*)rdy)[i] = 1;
        };

        // pass 1: lse for rows start+3t, then fill those rows in m order
        float lse_a = 0.f;
        if (t < count) lse_a = lse_row(start + 3 * t);
        const int n1 = (count < 64) ? count : 64;
        for (int m = 0; m < n1; ++m) fill_row(start + 3 * m, rdlane_f(lse_a, m));

        // pass 2: remaining rows (<=3)
        if (count > 64) {
            float lse_b = 0.f;
            if (64 + t < count) lse_b = lse_row(start + 3 * (64 + t));
            for (int m = 64; m < count; ++m) fill_row(start + 3 * m, rdlane_f(lse_b, m - 64));
        }
        return;
    }

    // ================= consumer: wave 0 — R14 main loop + scoped poll ======
    float v[4]     = {0.f, 0.f, 0.f, 0.f};
    int   pslot[4] = {0, 0, 0, 0};      // p for owned columns (0 = free)
    unsigned pp    = 0u;                // packed u8 shadow of pslot
    float uslot[4] = {0.f, 0.f, 0.f, 0.f};  // u of row matched to owned column
    float minv[4];
    int   waysl[4];
    int   usedm;
    float usent;
    int   watermark = 0;                // rows 0..watermark-1 known staged

    for (int i = 1; i <= QQ; ++i) {
        // ---- wait until rows 0..i-1 staged. Poll + compiler barrier ONLY
        //      while catching up; once watermark==QQ this is one scalar cmp.
        if (watermark < i) {
            do {
                int idx = watermark + t;
                int f = (idx < QQ) ? ((volatile int*)rdy)[idx] : 1;
                unsigned long long rm = __ballot(f != 0);
                unsigned long long nrm = ~rm;   // bit j set => lane j not ready
                int adv = nrm ? (int)__builtin_ctzll(nrm) : 64;
                if (adv == 0) __builtin_amdgcn_s_sleep(8);
                watermark += adv;
            } while (watermark < i);
            asm volatile("" ::: "memory");  // keep crow reads below the poll
        }

        minv[0] = minv[1] = minv[2] = minv[3] = INF;
        waysl[0] = waysl[1] = waysl[2] = waysl[3] = 0;
        usedm = 0;
        usent = 0.f;                    // u[i] == 0 at phase start
        int j0 = 0;
        float u0 = 0.f;                 // u[i0] for current iteration
        const float* crow = cm + (i - 1) * QQ;
        float c0 = crow[t];
        float c1 = crow[64 + t];
        float c2 = crow[128 + t];
        float c3 = crow[192 + t];       // pad keeps this in-bounds

        for (;;) {
            // ---- mark j0 used (owner lane)
            if (j0 > 0) {
                int s = (j0 - 1) >> 6;
                if (((j0 - 1) & 63) == t) usedm |= 1 << s;
            }

            // ---- scan owned columns (gated on !used: way entries freeze)
            float kv0, kv1, kv2, kv3;
            {
                float cur;
                cur = c0 - u0 - v[0];
                if (!(usedm & 1) && cur < minv[0]) { minv[0] = cur; waysl[0] = j0; }
                kv0 = (usedm & 1) ? INF : minv[0];
                cur = c1 - u0 - v[1];
                if (!(usedm & 2) && cur < minv[1]) { minv[1] = cur; waysl[1] = j0; }
                kv1 = (usedm & 2) ? INF : minv[1];
                cur = c2 - u0 - v[2];
                if (!(usedm & 4) && cur < minv[2]) { minv[2] = cur; waysl[2] = j0; }
                kv2 = (usedm & 4) ? INF : minv[2];
                cur = c3 - u0 - v[3];
                if (!(usedm & 8) && t < 8 && cur < minv[3]) { minv[3] = cur; waysl[3] = j0; }
                kv3 = ((usedm & 8) || t >= 8) ? INF : minv[3];
            }

            float gmin = wave_fmin_bcast(fminf(fminf(kv0, kv1), fminf(kv2, kv3)));
            float delta = gmin;

            // ---- smallest j with kv==gmin: k-major, lowest lane
            unsigned long long m0 = __ballot(kv0 == gmin);
            unsigned long long m1 = __ballot(kv1 == gmin);
            unsigned long long m2 = __ballot(kv2 == gmin);
            unsigned long long m3 = __ballot(kv3 == gmin);
            int j1;
            if (m0)      j1 = 1   + (int)__builtin_ctzll(m0);
            else if (m1) j1 = 65  + (int)__builtin_ctzll(m1);
            else if (m2) j1 = 129 + (int)__builtin_ctzll(m2);
            else         j1 = 193 + (int)__builtin_ctzll(m3);

            // ---- matched row + its dual from j1's owner lane (j1 uniform)
            int kk = (j1 - 1) >> 6, ln = (j1 - 1) & 63;
            float us = (kk == 0) ? uslot[0] : (kk == 1) ? uslot[1]
                      : (kk == 2) ? uslot[2] : uslot[3];
            // fast path: packed shadow, no select chain ahead of the readlane
            int pi = (int)(((unsigned)rdlane_i((int)pp, ln) >> (kk * 8)) & 255u);

            // ---- issue next row's reads NOW (cm immutable: no hazard);
            //      ~120cyc latency overlaps updates + u0n readlane below
            int nr = (pi > 0 ? pi : 1) - 1;
            const float* nrow = cm + nr * QQ;
            float n0 = nrow[t];
            float n1 = nrow[64 + t];
            float n2 = nrow[128 + t];
            float n3 = nrow[192 + t];

            float u0n = rdlane_f(us, ln);

            // ---- updates (identical fp-op sequence to reference)
#pragma unroll
            for (int k = 0; k < 4; ++k) {
                if (usedm & (1 << k)) {
                    v[k] -= delta;
                    uslot[k] += delta;               // == u[p[j]] += delta
                } else if (k < nval) {
                    minv[k] -= delta;
                }
            }
            usent += delta;                          // == u[i] += delta (sentinel)

            if (pi == 0) { j0 = j1; break; }
            j0 = j1; u0 = u0n;
            c0 = n0; c1 = n1; c2 = n2; c3 = n3;
        }

        // ---- augment: flip matching along alternating path (uniform walk;
        //      way/p/u served from registers via readlane; entries frozen)
        {
            int jj = j0;
            while (jj != 0) {
                int jm = jj - 1, km = jm >> 6, lm = jm & 63;
                int ws = (km == 0) ? waysl[0] : (km == 1) ? waysl[1]
                        : (km == 2) ? waysl[2] : waysl[3];
                int jn = rdlane_i(ws, lm);
                int pnew; float unew;
                if (jn == 0) {
                    pnew = i;                        // p[0] = i (sentinel)
                    unew = usent;                    // u[i] accumulated this phase
                } else {
                    int jm2 = jn - 1, kn = jm2 >> 6, ln2 = jm2 & 63;
                    int   ps2 = (kn == 0) ? pslot[0] : (kn == 1) ? pslot[1]
                               : (kn == 2) ? pslot[2] : pslot[3];
                    float us2 = (kn == 0) ? uslot[0] : (kn == 1) ? uslot[1]
                               : (kn == 2) ? uslot[2] : uslot[3];
                    pnew = rdlane_i(ps2, ln2);
                    unew = rdlane_f(us2, ln2);
                }
                if (lm == t) {
                    pslot[km] = pnew;
                    uslot[km] = unew;
                    int sh = km * 8;
                    pp = (pp & ~(255u << sh)) | ((unsigned)pnew << sh);
                }
                jj = jn;
            }
        }
    }

    // pslot[k] = row matched to owned column jc; emit per-row matched cost
#pragma unroll
    for (int k = 0; k < 4; ++k) {
        if (k < nval) {
            int jc = 1 + t + 64 * k;
            int row = pslot[k] - 1;
            out[b * QQ + row] = cm[row * QQ + (jc - 1)];
        }
    }
}

// ---------------------------------------------------------------------------
extern "C" void kernel_launch(void* const* d_in, const int* in_sizes, int n_in,
                              void* d_out, int out_size, void* d_ws, size_t ws_size,
                              hipStream_t stream) {
    const float* pred_cat  = (const float*)d_in[0];
    const float* pred_bbox = (const float*)d_in[1];
    const int*   tar_cat   = (const int*)d_in[2];
    const float* tar_bbox  = (const float*)d_in[3];
    float* out = (float*)d_out;
    (void)d_ws; (void)ws_size;

    hungarian_fused<<<BB, 256, 0, stream>>>(pred_cat, pred_bbox, tar_cat, tar_bbox, out);
}

// Round 11
// 1367.592 us; speedup vs baseline: 1.5493x; 1.0192x over previous
//
#include <hip/hip_runtime.h>
#include <math.h>

#define BB 128
#define QQ 200
#define CC 92
#define CMPAD (QQ * QQ + 64) // pad so c3 = crow[192+t] stays in-bounds for t<64

// ---------------------------------------------------------------------------
__device__ __forceinline__ int rdlane_i(int x, int l) { return __builtin_amdgcn_readlane(x, l); }
__device__ __forceinline__ float rdlane_f(float x, int l) {
    return __uint_as_float((unsigned)__builtin_amdgcn_readlane((int)__float_as_uint(x), l));
}

// wave64 float min-reduce via DPP (row_shr 1/2/4/8, row_bcast 15/31), result
// broadcast from lane 63 as an SGPR. Float domain (v_min_f32): jnp.argmin
// compares floats, so equality-ballot against this min reproduces its
// semantics exactly (incl. -0==+0). No NaNs in this data.
__device__ __forceinline__ float wave_fmin_bcast(float x) {
    float y;
#define DPPSTEP(ctrl) \
    y = __uint_as_float((unsigned)__builtin_amdgcn_update_dpp( \
            (int)__float_as_uint(x), (int)__float_as_uint(x), ctrl, 0xf, 0xf, false)); \
    x = fminf(x, y);
    DPPSTEP(0x111) DPPSTEP(0x112) DPPSTEP(0x114) DPPSTEP(0x118)
    DPPSTEP(0x142) DPPSTEP(0x143)
#undef DPPSTEP
    return rdlane_f(x, 63);
}

// ---------------------------------------------------------------------------
// R20 = R19's producer/consumer overlap with both measured stall mechanisms
// removed:
//   1. JOINT VECTORIZED LSE: all 4 waves compute lse lane-per-row BEFORE the
//      barrier (float4 loads, 23 per row, 368B row base is 16B-aligned; the
//      fmax/exp/log op ORDER is unchanged => bit-identical). Producers start
//      filling immediately after the barrier -- R19 serialized each
//      producer's whole 64-row lse pass ahead of its first fill (~30us
//      consumer stall).
//   2. TWO-EPOCH CONSUMER: catch-up epoch (poll + memory clobber + phase)
//      only while watermark < QQ; then a steady epoch with NO poll/branch/
//      clobber -- textually the R14 phase body (macro), restoring the
//      compiler's crow-load hoisting that R19's per-phase conditional
//      clobber blocked (~8us).
// Publish ordering unchanged (producer: lgkmcnt(0) drain then rdy[i]=1;
// consumer polls before reading). All fp expressions byte-identical =>
// trajectory bit-for-bit vs reference.
// Lane t owns columns j = 1+t+64k (k=0..3; k=3 valid only for t<8).
// ---------------------------------------------------------------------------

#define PHASE_BODY(I)                                                          \
    do {                                                                       \
        minv[0] = minv[1] = minv[2] = minv[3] = INF;                           \
        waysl[0] = waysl[1] = waysl[2] = waysl[3] = 0;                         \
        usedm = 0;                                                             \
        usent = 0.f;                                                           \
        int j0 = 0;                                                            \
        float u0 = 0.f;                                                        \
        const float* crow = cm + ((I) - 1) * QQ;                               \
        float c0 = crow[t];                                                    \
        float c1 = crow[64 + t];                                               \
        float c2 = crow[128 + t];                                              \
        float c3 = crow[192 + t];                                              \
        for (;;) {                                                             \
            if (j0 > 0) {                                                      \
                int s = (j0 - 1) >> 6;                                         \
                if (((j0 - 1) & 63) == t) usedm |= 1 << s;                     \
            }                                                                  \
            float kv0, kv1, kv2, kv3;                                          \
            {                                                                  \
                float cur;                                                     \
                cur = c0 - u0 - v[0];                                          \
                if (!(usedm & 1) && cur < minv[0]) { minv[0] = cur; waysl[0] = j0; } \
                kv0 = (usedm & 1) ? INF : minv[0];                             \
                cur = c1 - u0 - v[1];                                          \
                if (!(usedm & 2) && cur < minv[1]) { minv[1] = cur; waysl[1] = j0; } \
                kv1 = (usedm & 2) ? INF : minv[1];                             \
                cur = c2 - u0 - v[2];                                          \
                if (!(usedm & 4) && cur < minv[2]) { minv[2] = cur; waysl[2] = j0; } \
                kv2 = (usedm & 4) ? INF : minv[2];                             \
                cur = c3 - u0 - v[3];                                          \
                if (!(usedm & 8) && t < 8 && cur < minv[3]) { minv[3] = cur; waysl[3] = j0; } \
                kv3 = ((usedm & 8) || t >= 8) ? INF : minv[3];                 \
            }                                                                  \
            float gmin = wave_fmin_bcast(fminf(fminf(kv0, kv1), fminf(kv2, kv3))); \
            float delta = gmin;                                                \
            unsigned long long m0 = __ballot(kv0 == gmin);                     \
            unsigned long long m1 = __ballot(kv1 == gmin);                     \
            unsigned long long m2 = __ballot(kv2 == gmin);                     \
            unsigned long long m3 = __ballot(kv3 == gmin);                     \
            int j1;                                                            \
            if (m0)      j1 = 1   + (int)__builtin_ctzll(m0);                  \
            else if (m1) j1 = 65  + (int)__builtin_ctzll(m1);                  \
            else if (m2) j1 = 129 + (int)__builtin_ctzll(m2);                  \
            else         j1 = 193 + (int)__builtin_ctzll(m3);                  \
            int kk = (j1 - 1) >> 6, ln = (j1 - 1) & 63;                        \
            float us = (kk == 0) ? uslot[0] : (kk == 1) ? uslot[1]             \
                      : (kk == 2) ? uslot[2] : uslot[3];                       \
            int pi = (int)(((unsigned)rdlane_i((int)pp, ln) >> (kk * 8)) & 255u); \
            int nr = (pi > 0 ? pi : 1) - 1;                                    \
            const float* nrow = cm + nr * QQ;                                  \
            float n0 = nrow[t];                                                \
            float n1 = nrow[64 + t];                                           \
            float n2 = nrow[128 + t];                                          \
            float n3 = nrow[192 + t];                                          \
            float u0n = rdlane_f(us, ln);                                      \
            _Pragma("unroll")                                                  \
            for (int k = 0; k < 4; ++k) {                                      \
                if (usedm & (1 << k)) {                                        \
                    v[k] -= delta;                                             \
                    uslot[k] += delta;                                         \
                } else if (k < nval) {                                         \
                    minv[k] -= delta;                                          \
                }                                                              \
            }                                                                  \
            usent += delta;                                                    \
            if (pi == 0) { j0 = j1; break; }                                   \
            j0 = j1; u0 = u0n;                                                 \
            c0 = n0; c1 = n1; c2 = n2; c3 = n3;                                \
        }                                                                      \
        {                                                                      \
            int jj = j0;                                                       \
            while (jj != 0) {                                                  \
                int jm = jj - 1, km = jm >> 6, lm = jm & 63;                   \
                int ws = (km == 0) ? waysl[0] : (km == 1) ? waysl[1]           \
                        : (km == 2) ? waysl[2] : waysl[3];                     \
                int jn = rdlane_i(ws, lm);                                     \
                int pnew; float unew;                                          \
                if (jn == 0) {                                                 \
                    pnew = (I);                                                \
                    unew = usent;                                              \
                } else {                                                       \
                    int jm2 = jn - 1, kn = jm2 >> 6, ln2 = jm2 & 63;           \
                    int   ps2 = (kn == 0) ? pslot[0] : (kn == 1) ? pslot[1]    \
                               : (kn == 2) ? pslot[2] : pslot[3];              \
                    float us2 = (kn == 0) ? uslot[0] : (kn == 1) ? uslot[1]    \
                               : (kn == 2) ? uslot[2] : uslot[3];              \
                    pnew = rdlane_i(ps2, ln2);                                 \
                    unew = rdlane_f(us2, ln2);                                 \
                }                                                              \
                if (lm == t) {                                                 \
                    pslot[km] = pnew;                                          \
                    uslot[km] = unew;                                          \
                    int sh = km * 8;                                           \
                    pp = (pp & ~(255u << sh)) | ((unsigned)pnew << sh);        \
                }                                                              \
                jj = jn;                                                       \
            }                                                                  \
        }                                                                      \
    } while (0)

__global__ __launch_bounds__(256) void hungarian_fused(const float* __restrict__ pc,
                                                       const float* __restrict__ pb,
                                                       const int*   __restrict__ tc,
                                                       const float* __restrict__ tb,
                                                       float* __restrict__ out) {
    const int b = blockIdx.x;
    const int tid = threadIdx.x;
    const int w = tid >> 6;         // wave id 0..3
    const int t = tid & 63;         // lane id

    __shared__ __align__(16) float cm[CMPAD];
    __shared__ float lse_s[QQ];
    __shared__ int rdy[QQ];

    const float INF = 1e9f;
    const int nval = (t < 8) ? 4 : 3;   // slot k valid iff t+64k < 200

    if (tid < QQ) rdy[tid] = 0;

    // ---- joint lse: one row per thread, float4 loads (23 per row; row base
    //      368B = 16B-aligned). fmax/exp/log op ORDER identical to scalar
    //      reference => bit-identical values.
    if (tid < QQ) {
        const float4* row4 = reinterpret_cast<const float4*>(pc + ((size_t)(b * QQ + tid)) * CC);
        float m = -INFINITY;
        for (int c4 = 0; c4 < CC / 4; ++c4) {
            float4 x = row4[c4];
            m = fmaxf(fmaxf(fmaxf(fmaxf(m, x.x), x.y), x.z), x.w);
        }
        float s = 0.f;
        for (int c4 = 0; c4 < CC / 4; ++c4) {
            float4 x = row4[c4];
            s += expf(x.x - m); s += expf(x.y - m);
            s += expf(x.z - m); s += expf(x.w - m);
        }
        lse_s[tid] = m + logf(s);
    }
    __syncthreads();                    // only barrier; all threads reach it

    if (w > 0) {
        // ================= producers: waves 1..3, rows (w-1)+3m ============
        const int start = w - 1;                    // 0,1,2
        const int count = (QQ - start + 2) / 3;     // 67,67,66

        // per-lane column constants (owned columns j = t+64k)
        int   cls[4];
        float tbx[4][4];
#pragma unroll
        for (int k = 0; k < 4; ++k) {
            if (k < nval) {
                int jj = t + 64 * k;
                cls[k] = tc[b * QQ + jj];
                const float4 v4 = *reinterpret_cast<const float4*>(tb + ((size_t)(b * QQ + jj)) * 4);
                tbx[k][0] = v4.x; tbx[k][1] = v4.y; tbx[k][2] = v4.z; tbx[k][3] = v4.w;
            } else {
                cls[k] = 0;
                tbx[k][0] = tbx[k][1] = tbx[k][2] = tbx[k][3] = 0.f;
            }
        }

        // identical per-element fp expression/order as R14
        for (int m = 0; m < count; ++m) {
            const int i = start + 3 * m;
            const float4 pb4 = *reinterpret_cast<const float4*>(pb + ((size_t)(b * QQ + i)) * 4);
            const float pbb[4] = {pb4.x, pb4.y, pb4.z, pb4.w};
            const float lsei = lse_s[i];
            const float* pcrow = pc + ((size_t)(b * QQ + i)) * CC;
#pragma unroll
            for (int k = 0; k < 4; ++k) {
                if (k < nval) {
                    float ce = lsei - pcrow[cls[k]];
                    float sl1 = 0.f;
#pragma unroll
                    for (int d = 0; d < 4; ++d) {
                        float df = pbb[d] - tbx[k][d];
                        float ad = fabsf(df);
                        sl1 += (ad < 1.f) ? 0.5f * df * df : (ad - 0.5f);
                    }
                    float mask = (cls[k] != 0) ? 1.f : 0.f;
                    cm[i * QQ + t + 64 * k] = ce + sl1 * mask;
                }
            }
            // drain this wave's LDS writes (lgkm only: global loads stay in
            // flight), then publish. "memory" clobber stops compiler motion.
            asm volatile("s_waitcnt lgkmcnt(0)" ::: "memory");
            if (t == 0) ((volatile int*)rdy)[i] = 1;
        }
        return;
    }

    // ================= consumer: wave 0, two-epoch R14 main loop ===========
    float v[4]     = {0.f, 0.f, 0.f, 0.f};
    int   pslot[4] = {0, 0, 0, 0};      // p for owned columns (0 = free)
    unsigned pp    = 0u;                // packed u8 shadow of pslot
    float uslot[4] = {0.f, 0.f, 0.f, 0.f};  // u of row matched to owned column
    float minv[4];
    int   waysl[4];
    int   usedm;
    float usent;
    int   watermark = 0;                // rows 0..watermark-1 known staged
    int   i = 1;

    // catch-up epoch: poll + clobber, only while rows are still landing
    for (; i <= QQ && watermark < QQ; ++i) {
        while (watermark < i) {
            int idx = watermark + t;
            int f = (idx < QQ) ? ((volatile int*)rdy)[idx] : 1;
            unsigned long long rm = __ballot(f != 0);
            unsigned long long nrm = ~rm;   // bit j set => lane j not ready
            int adv = nrm ? (int)__builtin_ctzll(nrm) : 64;
            if (adv == 0) __builtin_amdgcn_s_sleep(8);
            watermark += adv;
        }
        asm volatile("" ::: "memory");  // keep crow reads below the poll
        PHASE_BODY(i);
    }
    // steady epoch: all rows staged; no poll, no branch, no clobber --
    // R14's exact codegen freedom restored
    for (; i <= QQ; ++i) {
        PHASE_BODY(i);
    }

    // pslot[k] = row matched to owned column jc; emit per-row matched cost
#pragma unroll
    for (int k = 0; k < 4; ++k) {
        if (k < nval) {
            int jc = 1 + t + 64 * k;
            int row = pslot[k] - 1;
            out[b * QQ + row] = cm[row * QQ + (jc - 1)];
        }
    }
}

// ---------------------------------------------------------------------------
extern "C" void kernel_launch(void* const* d_in, const int* in_sizes, int n_in,
                              void* d_out, int out_size, void* d_ws, size_t ws_size,
                              hipStream_t stream) {
    const float* pred_cat  = (const float*)d_in[0];
    const float* pred_bbox = (const float*)d_in[1];
    const int*   tar_cat   = (const int*)d_in[2];
    const float* tar_bbox  = (const float*)d_in[3];
    float* out = (float*)d_out;
    (void)d_ws; (void)ws_size;

    hungarian_fused<<<BB, 256, 0, stream>>>(pred_cat, pred_bbox, tar_cat, tar_bbox, out);
}